// Round 21
// baseline (238.528 us; speedup 1.0000x reference)
//
#include <hip/hip_runtime.h>
#include <cstdint>
#include <cstddef>

#define D_IN   256
#define D_OUT  128
#define NB_MAX 256    // row buckets = (n+255)>>8 ; requires n <= 65535 (row/col in 16 bits)
#define KV_CAP 12288  // per-bucket slab capacity (expected ~8163 for uniform rows)
#define NCB    8      // col buckets per row for within-row col ordering (cb = col>>13)
#define GQBLK  2048   // gather grid: 8 (branch,quarter) x 256 slots, all co-resident

typedef short bf16x8 __attribute__((ext_vector_type(8)));
typedef float f32x4  __attribute__((ext_vector_type(4)));

union Frag { bf16x8 v; uint32_t u[4]; };

struct Branch {
  const float* X;
  const int*   idx;
  const float* val;
  uint16_t* H;          // flat [n][128] bf16
  int*   ptr;           // n+1
  int*   bucketCur;     // NB_MAX (zeroed before bin; holds counts after)
  uint64_t* kv2;        // NB_MAX*KV_CAP padded slabs: (val32 | row16 | col16)
  uint32_t* csr4;       // ne compact, row-grouped + col-bucket-sorted: (val_bf16<<16 | col)
  float* out;
};

__device__ inline uint32_t cvt_pk_bf16(float lo, float hi) {
  uint32_t r;
  asm("v_cvt_pk_bf16_f32 %0, %1, %2" : "=v"(r) : "v"(lo), "v"(hi));
  return r;
}

// exclusive prefix over 256 threads (4 waves)
__device__ inline int block_scan256_excl(int v, int tid) {
  int lane = tid & 63, w = tid >> 6;
  int s = v;
  #pragma unroll
  for (int off = 1; off < 64; off <<= 1) {
    int t = __shfl_up(s, off);
    if (lane >= off) s += t;
  }
  __shared__ int wsum[4];
  if (lane == 63) wsum[w] = s;
  __syncthreads();
  int add = 0;
  #pragma unroll
  for (int i = 0; i < 4; ++i) add += (i < w) ? wsum[i] : 0;
  return s + add - v;
}

// ---------------- W prep: W[256][128] fp32 -> WT3 B-frag units (bf16, RNE) ----------------
__global__ __launch_bounds__(256) void wprep3_kernel(const float* __restrict__ W,
                                                     uint16_t* __restrict__ WT3) {
  int n = blockIdx.x;    // 0..127
  int t = threadIdx.x;   // 0..255
  int ks = t >> 5, g = (t >> 3) & 3, j = t & 7;
  int k = ks * 32 + ((j < 4) ? (4 * g + j) : (16 + 4 * g + (j - 4)));
  uint32_t u = __float_as_uint(W[k * 128 + n]);
  WT3[(size_t)((ks * 4 + g) * 128 + n) * 8 + j] =
      (uint16_t)((u + 0x7FFFu + ((u >> 16) & 1u)) >> 16);
}

// ---------------- fused: z=0 bin (padded-slab scatter), z=1 GEMM (LDS-staged MFMA) ------
__global__ __launch_bounds__(256, 3) void bin_gemm_kernel(const uint16_t* __restrict__ WT3,
                                                          Branch b0, Branch b1,
                                                          int n_rows, int ne, int nb) {
  Branch b = blockIdx.y ? b1 : b0;
  const int t = threadIdx.x;
  __shared__ uint8_t smem[32768];

  if (blockIdx.z == 0) {
    // ---- bin body: LDS hist -> one bucket-slab reservation -> grouped writes ----
    int* hist  = (int*)smem;
    int* lcur  = hist + NB_MAX;
    int* gbase = lcur + NB_MAX;
    const int base = blockIdx.x * 4096;
    if (base >= ne) return;
    if (t < nb) hist[t] = 0;
    __syncthreads();
    uint64_t kv2[16];
    int bkt[16];
    #pragma unroll
    for (int i = 0; i < 16; ++i) {
      int e = base + i * 256 + t;
      bkt[i] = -1;
      if (e < ne) {
        int2 rc = ((const int2*)b.idx)[e];
        uint32_t v = __float_as_uint(b.val[e]);
        kv2[i] = ((uint64_t)v << 32) | ((uint32_t)rc.x << 16) | (uint32_t)rc.y;
        bkt[i] = rc.x >> 8;
        atomicAdd(&hist[bkt[i]], 1);
      }
    }
    __syncthreads();
    if (t < nb) {
      int h = hist[t];
      gbase[t] = h ? atomicAdd(&b.bucketCur[t], h) : 0;
      lcur[t] = 0;
    }
    __syncthreads();
    #pragma unroll
    for (int i = 0; i < 16; ++i) {
      if (bkt[i] >= 0) {
        int pos = gbase[bkt[i]] + atomicAdd(&lcur[bkt[i]], 1);
        if (pos < KV_CAP)
          b.kv2[(size_t)bkt[i] * KV_CAP + pos] = kv2[i];
      }
    }
    return;
  }

  // ---- gemm body: LDS-staged double-buffered ----
  const int w = t >> 6, l = t & 63;
  const int c = l & 15, g = l >> 4;
  const int row0 = blockIdx.x * 128;
  if (row0 >= n_rows) return;

  auto stage = [&](int ks, int buf) {
    #pragma unroll
    for (int i = 0; i < 4; ++i) {
      int row = i * 32 + (t >> 3);
      int gr = row0 + row; if (gr > n_rows - 1) gr = n_rows - 1;
      int kb = ((t & 7) * 16) ^ ((row & 7) << 4);   // swizzled byte within 128B row
      const float* src = b.X + (size_t)gr * D_IN + ks * 32 + (kb >> 2);
      __builtin_amdgcn_global_load_lds(
          (const __attribute__((address_space(1))) uint32_t*)src,
          (__attribute__((address_space(3))) uint32_t*)&smem[buf * 16384 + i * 4096 + t * 16],
          16, 0, 0);
    }
  };

  const uint4* Bp = (const uint4*)WT3;

  f32x4 acc[2][8];
  #pragma unroll
  for (int i = 0; i < 2; ++i)
    #pragma unroll
    for (int j = 0; j < 8; ++j) acc[i][j] = (f32x4){0.f, 0.f, 0.f, 0.f};

  stage(0, 0);
  asm volatile("s_waitcnt vmcnt(0)" ::: "memory");
  __syncthreads();

  for (int ks = 0; ks < 8; ++ks) {
    int buf = ks & 1;
    uint4 bu[8];
    #pragma unroll
    for (int nf = 0; nf < 8; ++nf)
      bu[nf] = Bp[(ks * 4 + g) * 128 + nf * 16 + c];
    if (ks < 7) stage(ks + 1, buf ^ 1);

    Frag A[2];
    #pragma unroll
    for (int rf = 0; rf < 2; ++rf) {
      int row = w * 32 + rf * 16 + c;
      const uint8_t* base = &smem[buf * 16384 + row * 128];
      int swz = (row & 7) << 4;
      float4 x0 = *(const float4*)(base + ((g * 16) ^ swz));
      float4 x1 = *(const float4*)(base + ((64 + g * 16) ^ swz));
      A[rf].u[0] = cvt_pk_bf16(x0.x, x0.y);
      A[rf].u[1] = cvt_pk_bf16(x0.z, x0.w);
      A[rf].u[2] = cvt_pk_bf16(x1.x, x1.y);
      A[rf].u[3] = cvt_pk_bf16(x1.z, x1.w);
    }

    #pragma unroll
    for (int nf = 0; nf < 8; ++nf) {
      Frag B;
      B.u[0] = bu[nf].x; B.u[1] = bu[nf].y; B.u[2] = bu[nf].z; B.u[3] = bu[nf].w;
      acc[0][nf] = __builtin_amdgcn_mfma_f32_16x16x32_bf16(A[0].v, B.v, acc[0][nf], 0, 0, 0);
      acc[1][nf] = __builtin_amdgcn_mfma_f32_16x16x32_bf16(A[1].v, B.v, acc[1][nf], 0, 0, 0);
    }

    if (ks < 7) {
      asm volatile("s_waitcnt vmcnt(0)" ::: "memory");
      __syncthreads();
    }
  }

  #pragma unroll
  for (int rf = 0; rf < 2; ++rf)
    #pragma unroll
    for (int nf = 0; nf < 8; ++nf)
      #pragma unroll
      for (int r = 0; r < 4; ++r) {
        float v = acc[rf][nf][r];
        float o = __shfl_xor(v, 1);
        uint32_t pk = cvt_pk_bf16(v, o);       // valid at even c: cols (c, c+1)
        uint32_t pk2 = __shfl_xor(pk, 2);      // partner: cols (c+2, c+3)
        int row_g = row0 + w * 32 + rf * 16 + 4 * g + r;
        if ((c & 3) == 0 && row_g < n_rows) {
          uint2 d; d.x = pk; d.y = pk2;
          *(uint2*)(b.H + (size_t)row_g * D_OUT + nf * 16 + c) = d;
        }
      }
}

// ---------------- per-bucket CSR finalize: (row, col-bucket) ordered scatter ----------------
__global__ __launch_bounds__(256) void bucket_csr_kernel(Branch b0, Branch b1, int n, int nb) {
  Branch b = blockIdx.y ? b1 : b0;
  const int bkt = blockIdx.x;
  const int tid = threadIdx.x;
  __shared__ int sbase[NB_MAX];
  __shared__ int hist2[256 * NCB];
  __shared__ int cur2[256 * NCB];

  int cntv = (tid < nb) ? b.bucketCur[tid] : 0;
  if (cntv > KV_CAP) cntv = KV_CAP;
  int excl0 = block_scan256_excl(cntv, tid);
  if (tid < nb) sbase[tid] = excl0;
  if (bkt == 0 && tid == nb - 1) b.ptr[n] = excl0 + cntv;   // == ne
  __syncthreads();

  const int dstBase = sbase[bkt];
  int cnt = b.bucketCur[bkt];
  if (cnt > KV_CAP) cnt = KV_CAP;
  const uint64_t* src = b.kv2 + (size_t)bkt * KV_CAP;

  #pragma unroll
  for (int i = 0; i < NCB; ++i) hist2[i * 256 + tid] = 0;
  __syncthreads();
  for (int e = tid; e < cnt; e += 256) {
    uint64_t kv = src[e];
    int lr = (int)((kv >> 16) & 0xFF);
    int cb = (int)(kv & 0xFFFFu) >> 13;
    atomicAdd(&hist2[lr * NCB + cb], 1);
  }
  __syncthreads();

  int h[NCB], rowtot = 0;
  #pragma unroll
  for (int j = 0; j < NCB; ++j) { h[j] = hist2[tid * NCB + j]; rowtot += h[j]; }
  int rowExcl = block_scan256_excl(rowtot, tid);
  int row = bkt * 256 + tid;
  if (row < n) b.ptr[row] = dstBase + rowExcl;
  int run = dstBase + rowExcl;
  #pragma unroll
  for (int j = 0; j < NCB; ++j) { cur2[tid * NCB + j] = run; run += h[j]; }
  __syncthreads();

  for (int e = tid; e < cnt; e += 256) {
    uint64_t kv = src[e];
    int lr = (int)((kv >> 16) & 0xFF);
    uint32_t col = (uint32_t)(kv & 0xFFFFu);
    int cb = (int)col >> 13;
    uint32_t u = (uint32_t)(kv >> 32);
    uint32_t vbf = (u + 0x7FFFu + ((u >> 16) & 1u)) & 0xFFFF0000u;  // RNE bf16 in high16
    int pos = atomicAdd(&cur2[lr * NCB + cb], 1);
    b.csr4[pos] = vbf | col;
  }
}

// ---------------- col-quarter gather + relu: XCD-pinned working sets ----------------
// bid&7 -> (branch, quarter): XCD x only touches H lines at byte offset q*64 of each row
// (3.2 MB/XCD < 4 MB L2). 4 lanes/row x uint4; 64 rows per chunk; grid-stride chunks.
// All 2048 blocks co-resident (48 VGPR, 0 LDS) -> %8 XCD mapping stable for whole kernel.
__global__ __launch_bounds__(256) void gather_q_kernel(Branch b0, Branch b1, int n_rows) {
  const int xid  = blockIdx.x & 7;
  const int br   = xid >> 2;
  const int q    = xid & 3;
  const int slot = blockIdx.x >> 3;               // 0..255
  Branch b = br ? b1 : b0;
  const int lane4 = threadIdx.x & 3;              // uint4 within the 64B quarter
  const int rloc  = threadIdx.x >> 2;             // 0..63
  const uint4* Hq = (const uint4*)b.H;            // 16 uint4 per row
  const int hoff = q * 4 + lane4;                 // uint4 index within row

  for (int chunk = slot; chunk * 64 < n_rows; chunk += 256) {
    int row = chunk * 64 + rloc;
    if (row >= n_rows) continue;
    int beg = b.ptr[row], end = b.ptr[row + 1];
    float4 acc0 = make_float4(0.f, 0.f, 0.f, 0.f);
    float4 acc1 = make_float4(0.f, 0.f, 0.f, 0.f);

    auto fma_h = [&](uint32_t k, uint4 h) {
      float v = __uint_as_float(k & 0xFFFF0000u);   // bf16 val in high bits
      float f0 = __uint_as_float(h.x << 16), f1 = __uint_as_float(h.x & 0xFFFF0000u);
      float f2 = __uint_as_float(h.y << 16), f3 = __uint_as_float(h.y & 0xFFFF0000u);
      float f4 = __uint_as_float(h.z << 16), f5 = __uint_as_float(h.z & 0xFFFF0000u);
      float f6 = __uint_as_float(h.w << 16), f7 = __uint_as_float(h.w & 0xFFFF0000u);
      acc0.x = fmaf(f0, v, acc0.x); acc0.y = fmaf(f1, v, acc0.y);
      acc0.z = fmaf(f2, v, acc0.z); acc0.w = fmaf(f3, v, acc0.w);
      acc1.x = fmaf(f4, v, acc1.x); acc1.y = fmaf(f5, v, acc1.y);
      acc1.z = fmaf(f6, v, acc1.z); acc1.w = fmaf(f7, v, acc1.w);
    };

    int e = beg;
    for (; e + 8 <= end; e += 8) {
      uint32_t k[8];
      #pragma unroll
      for (int i = 0; i < 8; ++i) k[i] = b.csr4[e + i];
      uint4 h[8];
      #pragma unroll
      for (int i = 0; i < 8; ++i)
        h[i] = Hq[(size_t)(k[i] & 0xFFFFu) * 16 + hoff];
      #pragma unroll
      for (int i = 0; i < 8; ++i) fma_h(k[i], h[i]);
    }
    for (; e < end; ++e) {
      uint32_t k = b.csr4[e];
      uint4 h = Hq[(size_t)(k & 0xFFFFu) * 16 + hoff];
      fma_h(k, h);
    }

    float4 o0, o1;
    o0.x = fmaxf(acc0.x, 0.f); o0.y = fmaxf(acc0.y, 0.f);
    o0.z = fmaxf(acc0.z, 0.f); o0.w = fmaxf(acc0.w, 0.f);
    o1.x = fmaxf(acc1.x, 0.f); o1.y = fmaxf(acc1.y, 0.f);
    o1.z = fmaxf(acc1.z, 0.f); o1.w = fmaxf(acc1.w, 0.f);
    float* orow = b.out + (size_t)row * D_OUT + q * 32 + lane4 * 8;
    *(float4*)orow = o0;
    *(float4*)(orow + 4) = o1;
  }
}

extern "C" void kernel_launch(void* const* d_in, const int* in_sizes, int n_in,
                              void* d_out, int out_size, void* d_ws, size_t ws_size,
                              hipStream_t stream) {
  const float* inp_s = (const float*)d_in[0];
  const float* inp_t = (const float*)d_in[1];
  const int*   idx_s = (const int*)d_in[2];
  const float* val_s = (const float*)d_in[3];
  const int*   idx_t = (const int*)d_in[4];
  const float* val_t = (const float*)d_in[5];
  const float* W     = (const float*)d_in[6];
  float* out = (float*)d_out;

  const int n  = in_sizes[0] / D_IN;   // 50000
  const int ne = in_sizes[3];          // 1600000
  const int nb = (n + 255) >> 8;       // 196

  char* p = (char*)d_ws;
  auto alloc = [&](size_t bytes) -> char* {
    char* r = p;
    p += (bytes + 255) & ~(size_t)255;
    return r;
  };
  uint16_t* H_s    = (uint16_t*)alloc((size_t)n * D_OUT * 2);
  uint16_t* H_t    = (uint16_t*)alloc((size_t)n * D_OUT * 2);
  uint16_t* WT3    = (uint16_t*)alloc((size_t)128 * 256 * 2);
  int* ptr_s       = (int*)alloc((size_t)(n + 1) * 4);
  int* ptr_t       = (int*)alloc((size_t)(n + 1) * 4);
  int* bcur        = (int*)alloc((size_t)2 * NB_MAX * 4);   // one memset covers both
  int* bcur_s      = bcur;
  int* bcur_t      = bcur + NB_MAX;
  uint64_t* kv2_s  = (uint64_t*)alloc((size_t)NB_MAX * KV_CAP * 8);
  uint64_t* kv2_t  = (uint64_t*)alloc((size_t)NB_MAX * KV_CAP * 8);
  uint32_t* c4_s   = (uint32_t*)alloc((size_t)ne * 4);
  uint32_t* c4_t   = (uint32_t*)alloc((size_t)ne * 4);

  Branch bs = { inp_s, idx_s, val_s, H_s, ptr_s, bcur_s, kv2_s, c4_s, out };
  Branch bt = { inp_t, idx_t, val_t, H_t, ptr_t, bcur_t, kv2_t, c4_t,
                out + (size_t)n * D_OUT };

  const int nblkE = (ne + 4095) / 4096;            // 391
  const int nblkG = (n + 127) / 128;               // 391
  const int nblkF = nblkE > nblkG ? nblkE : nblkG;

  hipMemsetAsync(bcur, 0, (size_t)2 * NB_MAX * 4, stream);
  wprep3_kernel<<<dim3(128), 256, 0, stream>>>(W, WT3);
  bin_gemm_kernel<<<dim3(nblkF, 2, 2), 256, 0, stream>>>(WT3, bs, bt, n, ne, nb);
  bucket_csr_kernel<<<dim3(nb, 2), 256, 0, stream>>>(bs, bt, n, nb);
  gather_q_kernel<<<dim3(GQBLK), 256, 0, stream>>>(bs, bt, n);
}

// Round 22
// 195.513 us; speedup vs baseline: 1.2200x; 1.2200x over previous
//
#include <hip/hip_runtime.h>
#include <cstdint>
#include <cstddef>

#define D_IN   256
#define D_OUT  128
#define NB_MAX 256    // row buckets = (n+255)>>8 ; requires n <= 65535 (row/col in 16 bits)
#define KV_CAP 12288  // per-bucket slab capacity (expected ~8163 for uniform rows)
#define NCB    8      // col buckets per row for within-row col ordering (cb = col>>13)

typedef short bf16x8 __attribute__((ext_vector_type(8)));
typedef float f32x4  __attribute__((ext_vector_type(4)));

union Frag { bf16x8 v; uint32_t u[4]; };

struct Branch {
  const float* X;
  const int*   idx;
  const float* val;
  uint16_t* H;          // flat [n][128] bf16
  int*   ptr;           // n+1
  int*   bucketCur;     // NB_MAX (zeroed before bin; holds counts after)
  uint64_t* kv2;        // NB_MAX*KV_CAP padded slabs: (val32 | row16 | col16)
  uint32_t* csr4;       // ne compact, row-grouped + col-bucket-sorted: (val_bf16<<16 | col)
  float* out;
};

__device__ inline uint32_t cvt_pk_bf16(float lo, float hi) {
  uint32_t r;
  asm("v_cvt_pk_bf16_f32 %0, %1, %2" : "=v"(r) : "v"(lo), "v"(hi));
  return r;
}

// exclusive prefix over 256 threads (4 waves)
__device__ inline int block_scan256_excl(int v, int tid) {
  int lane = tid & 63, w = tid >> 6;
  int s = v;
  #pragma unroll
  for (int off = 1; off < 64; off <<= 1) {
    int t = __shfl_up(s, off);
    if (lane >= off) s += t;
  }
  __shared__ int wsum[4];
  if (lane == 63) wsum[w] = s;
  __syncthreads();
  int add = 0;
  #pragma unroll
  for (int i = 0; i < 4; ++i) add += (i < w) ? wsum[i] : 0;
  return s + add - v;
}

// ---------------- W prep: W[256][128] fp32 -> WT3 B-frag units (bf16, RNE) ----------------
__global__ __launch_bounds__(256) void wprep3_kernel(const float* __restrict__ W,
                                                     uint16_t* __restrict__ WT3) {
  int n = blockIdx.x;    // 0..127
  int t = threadIdx.x;   // 0..255
  int ks = t >> 5, g = (t >> 3) & 3, j = t & 7;
  int k = ks * 32 + ((j < 4) ? (4 * g + j) : (16 + 4 * g + (j - 4)));
  uint32_t u = __float_as_uint(W[k * 128 + n]);
  WT3[(size_t)((ks * 4 + g) * 128 + n) * 8 + j] =
      (uint16_t)((u + 0x7FFFu + ((u >> 16) & 1u)) >> 16);
}

// ---------------- fused: z=0 bin (padded-slab scatter), z=1 GEMM (LDS-staged MFMA) ------
__global__ __launch_bounds__(256, 3) void bin_gemm_kernel(const uint16_t* __restrict__ WT3,
                                                          Branch b0, Branch b1,
                                                          int n_rows, int ne, int nb) {
  Branch b = blockIdx.y ? b1 : b0;
  const int t = threadIdx.x;
  __shared__ uint8_t smem[32768];

  if (blockIdx.z == 0) {
    // ---- bin body: LDS hist -> one bucket-slab reservation -> grouped writes ----
    int* hist  = (int*)smem;
    int* lcur  = hist + NB_MAX;
    int* gbase = lcur + NB_MAX;
    const int base = blockIdx.x * 4096;
    if (base >= ne) return;
    if (t < nb) hist[t] = 0;
    __syncthreads();
    uint64_t kv2[16];
    int bkt[16];
    #pragma unroll
    for (int i = 0; i < 16; ++i) {
      int e = base + i * 256 + t;
      bkt[i] = -1;
      if (e < ne) {
        int2 rc = ((const int2*)b.idx)[e];
        uint32_t v = __float_as_uint(b.val[e]);
        kv2[i] = ((uint64_t)v << 32) | ((uint32_t)rc.x << 16) | (uint32_t)rc.y;
        bkt[i] = rc.x >> 8;
        atomicAdd(&hist[bkt[i]], 1);
      }
    }
    __syncthreads();
    if (t < nb) {
      int h = hist[t];
      gbase[t] = h ? atomicAdd(&b.bucketCur[t], h) : 0;
      lcur[t] = 0;
    }
    __syncthreads();
    #pragma unroll
    for (int i = 0; i < 16; ++i) {
      if (bkt[i] >= 0) {
        int pos = gbase[bkt[i]] + atomicAdd(&lcur[bkt[i]], 1);
        if (pos < KV_CAP)
          b.kv2[(size_t)bkt[i] * KV_CAP + pos] = kv2[i];
      }
    }
    return;
  }

  // ---- gemm body: LDS-staged double-buffered ----
  const int w = t >> 6, l = t & 63;
  const int c = l & 15, g = l >> 4;
  const int row0 = blockIdx.x * 128;
  if (row0 >= n_rows) return;

  auto stage = [&](int ks, int buf) {
    #pragma unroll
    for (int i = 0; i < 4; ++i) {
      int row = i * 32 + (t >> 3);
      int gr = row0 + row; if (gr > n_rows - 1) gr = n_rows - 1;
      int kb = ((t & 7) * 16) ^ ((row & 7) << 4);   // swizzled byte within 128B row
      const float* src = b.X + (size_t)gr * D_IN + ks * 32 + (kb >> 2);
      __builtin_amdgcn_global_load_lds(
          (const __attribute__((address_space(1))) uint32_t*)src,
          (__attribute__((address_space(3))) uint32_t*)&smem[buf * 16384 + i * 4096 + t * 16],
          16, 0, 0);
    }
  };

  const uint4* Bp = (const uint4*)WT3;

  f32x4 acc[2][8];
  #pragma unroll
  for (int i = 0; i < 2; ++i)
    #pragma unroll
    for (int j = 0; j < 8; ++j) acc[i][j] = (f32x4){0.f, 0.f, 0.f, 0.f};

  stage(0, 0);
  asm volatile("s_waitcnt vmcnt(0)" ::: "memory");
  __syncthreads();

  for (int ks = 0; ks < 8; ++ks) {
    int buf = ks & 1;
    uint4 bu[8];
    #pragma unroll
    for (int nf = 0; nf < 8; ++nf)
      bu[nf] = Bp[(ks * 4 + g) * 128 + nf * 16 + c];
    if (ks < 7) stage(ks + 1, buf ^ 1);

    Frag A[2];
    #pragma unroll
    for (int rf = 0; rf < 2; ++rf) {
      int row = w * 32 + rf * 16 + c;
      const uint8_t* base = &smem[buf * 16384 + row * 128];
      int swz = (row & 7) << 4;
      float4 x0 = *(const float4*)(base + ((g * 16) ^ swz));
      float4 x1 = *(const float4*)(base + ((64 + g * 16) ^ swz));
      A[rf].u[0] = cvt_pk_bf16(x0.x, x0.y);
      A[rf].u[1] = cvt_pk_bf16(x0.z, x0.w);
      A[rf].u[2] = cvt_pk_bf16(x1.x, x1.y);
      A[rf].u[3] = cvt_pk_bf16(x1.z, x1.w);
    }

    #pragma unroll
    for (int nf = 0; nf < 8; ++nf) {
      Frag B;
      B.u[0] = bu[nf].x; B.u[1] = bu[nf].y; B.u[2] = bu[nf].z; B.u[3] = bu[nf].w;
      acc[0][nf] = __builtin_amdgcn_mfma_f32_16x16x32_bf16(A[0].v, B.v, acc[0][nf], 0, 0, 0);
      acc[1][nf] = __builtin_amdgcn_mfma_f32_16x16x32_bf16(A[1].v, B.v, acc[1][nf], 0, 0, 0);
    }

    if (ks < 7) {
      asm volatile("s_waitcnt vmcnt(0)" ::: "memory");
      __syncthreads();
    }
  }

  #pragma unroll
  for (int rf = 0; rf < 2; ++rf)
    #pragma unroll
    for (int nf = 0; nf < 8; ++nf)
      #pragma unroll
      for (int r = 0; r < 4; ++r) {
        float v = acc[rf][nf][r];
        float o = __shfl_xor(v, 1);
        uint32_t pk = cvt_pk_bf16(v, o);       // valid at even c: cols (c, c+1)
        uint32_t pk2 = __shfl_xor(pk, 2);      // partner: cols (c+2, c+3)
        int row_g = row0 + w * 32 + rf * 16 + 4 * g + r;
        if ((c & 3) == 0 && row_g < n_rows) {
          uint2 d; d.x = pk; d.y = pk2;
          *(uint2*)(b.H + (size_t)row_g * D_OUT + nf * 16 + c) = d;
        }
      }
}

// ---------------- per-bucket CSR finalize: (row, col-bucket) ordered scatter ----------------
__global__ __launch_bounds__(256) void bucket_csr_kernel(Branch b0, Branch b1, int n, int nb) {
  Branch b = blockIdx.y ? b1 : b0;
  const int bkt = blockIdx.x;
  const int tid = threadIdx.x;
  __shared__ int sbase[NB_MAX];
  __shared__ int hist2[256 * NCB];
  __shared__ int cur2[256 * NCB];

  int cntv = (tid < nb) ? b.bucketCur[tid] : 0;
  if (cntv > KV_CAP) cntv = KV_CAP;
  int excl0 = block_scan256_excl(cntv, tid);
  if (tid < nb) sbase[tid] = excl0;
  if (bkt == 0 && tid == nb - 1) b.ptr[n] = excl0 + cntv;   // == ne
  __syncthreads();

  const int dstBase = sbase[bkt];
  int cnt = b.bucketCur[bkt];
  if (cnt > KV_CAP) cnt = KV_CAP;
  const uint64_t* src = b.kv2 + (size_t)bkt * KV_CAP;

  #pragma unroll
  for (int i = 0; i < NCB; ++i) hist2[i * 256 + tid] = 0;
  __syncthreads();
  for (int e = tid; e < cnt; e += 256) {
    uint64_t kv = src[e];
    int lr = (int)((kv >> 16) & 0xFF);
    int cb = (int)(kv & 0xFFFFu) >> 13;
    atomicAdd(&hist2[lr * NCB + cb], 1);
  }
  __syncthreads();

  int h[NCB], rowtot = 0;
  #pragma unroll
  for (int j = 0; j < NCB; ++j) { h[j] = hist2[tid * NCB + j]; rowtot += h[j]; }
  int rowExcl = block_scan256_excl(rowtot, tid);
  int row = bkt * 256 + tid;
  if (row < n) b.ptr[row] = dstBase + rowExcl;
  int run = dstBase + rowExcl;
  #pragma unroll
  for (int j = 0; j < NCB; ++j) { cur2[tid * NCB + j] = run; run += h[j]; }
  __syncthreads();

  for (int e = tid; e < cnt; e += 256) {
    uint64_t kv = src[e];
    int lr = (int)((kv >> 16) & 0xFF);
    uint32_t col = (uint32_t)(kv & 0xFFFFu);
    int cb = (int)col >> 13;
    uint32_t u = (uint32_t)(kv >> 32);
    uint32_t vbf = (u + 0x7FFFu + ((u >> 16) & 1u)) & 0xFFFF0000u;  // RNE bf16 in high16
    int pos = atomicAdd(&cur2[lr * NCB + cb], 1);
    b.csr4[pos] = vbf | col;
  }
}

// ---------------- per-row gather + relu (16 lanes/row, uint4 H loads, unroll-8) ----------
// XCD routing: branch = (bid&7)>>2  [XCD = bid % 8]
__global__ __launch_bounds__(256) void gather_kernel(Branch b0, Branch b1, int n_rows) {
  const int bid = blockIdx.x;
  const int br  = (bid & 7) >> 2;
  const int local = (bid >> 3) * 4 + (bid & 3);
  Branch b = br ? b1 : b0;
  int row = local * 16 + (threadIdx.x >> 4);
  if (row >= n_rows) return;
  int lane4 = threadIdx.x & 15;          // uint4 index within H row (16 per row)
  const uint4* Hq = (const uint4*)b.H;
  int beg = b.ptr[row], end = b.ptr[row + 1];
  float4 acc0 = make_float4(0.f, 0.f, 0.f, 0.f);
  float4 acc1 = make_float4(0.f, 0.f, 0.f, 0.f);

  auto fma_h = [&](uint32_t k, uint4 h) {
    float v = __uint_as_float(k & 0xFFFF0000u);   // bf16 val in high bits
    float f0 = __uint_as_float(h.x << 16), f1 = __uint_as_float(h.x & 0xFFFF0000u);
    float f2 = __uint_as_float(h.y << 16), f3 = __uint_as_float(h.y & 0xFFFF0000u);
    float f4 = __uint_as_float(h.z << 16), f5 = __uint_as_float(h.z & 0xFFFF0000u);
    float f6 = __uint_as_float(h.w << 16), f7 = __uint_as_float(h.w & 0xFFFF0000u);
    acc0.x = fmaf(f0, v, acc0.x); acc0.y = fmaf(f1, v, acc0.y);
    acc0.z = fmaf(f2, v, acc0.z); acc0.w = fmaf(f3, v, acc0.w);
    acc1.x = fmaf(f4, v, acc1.x); acc1.y = fmaf(f5, v, acc1.y);
    acc1.z = fmaf(f6, v, acc1.z); acc1.w = fmaf(f7, v, acc1.w);
  };

  int e = beg;
  for (; e + 8 <= end; e += 8) {
    uint32_t k[8];
    #pragma unroll
    for (int i = 0; i < 8; ++i) k[i] = b.csr4[e + i];
    uint4 h[8];
    #pragma unroll
    for (int i = 0; i < 8; ++i)
      h[i] = Hq[(size_t)(k[i] & 0xFFFFu) * 16 + lane4];
    #pragma unroll
    for (int i = 0; i < 8; ++i) fma_h(k[i], h[i]);
  }
  for (; e < end; ++e) {
    uint32_t k = b.csr4[e];
    uint4 h = Hq[(size_t)(k & 0xFFFFu) * 16 + lane4];
    fma_h(k, h);
  }

  float4 o0, o1;
  o0.x = fmaxf(acc0.x, 0.f); o0.y = fmaxf(acc0.y, 0.f);
  o0.z = fmaxf(acc0.z, 0.f); o0.w = fmaxf(acc0.w, 0.f);
  o1.x = fmaxf(acc1.x, 0.f); o1.y = fmaxf(acc1.y, 0.f);
  o1.z = fmaxf(acc1.z, 0.f); o1.w = fmaxf(acc1.w, 0.f);
  float* orow = b.out + (size_t)row * D_OUT + lane4 * 8;
  *(float4*)orow = o0;
  *(float4*)(orow + 4) = o1;
}

extern "C" void kernel_launch(void* const* d_in, const int* in_sizes, int n_in,
                              void* d_out, int out_size, void* d_ws, size_t ws_size,
                              hipStream_t stream) {
  const float* inp_s = (const float*)d_in[0];
  const float* inp_t = (const float*)d_in[1];
  const int*   idx_s = (const int*)d_in[2];
  const float* val_s = (const float*)d_in[3];
  const int*   idx_t = (const int*)d_in[4];
  const float* val_t = (const float*)d_in[5];
  const float* W     = (const float*)d_in[6];
  float* out = (float*)d_out;

  const int n  = in_sizes[0] / D_IN;   // 50000
  const int ne = in_sizes[3];          // 1600000
  const int nb = (n + 255) >> 8;       // 196

  char* p = (char*)d_ws;
  auto alloc = [&](size_t bytes) -> char* {
    char* r = p;
    p += (bytes + 255) & ~(size_t)255;
    return r;
  };
  uint16_t* H_s    = (uint16_t*)alloc((size_t)n * D_OUT * 2);
  uint16_t* H_t    = (uint16_t*)alloc((size_t)n * D_OUT * 2);
  uint16_t* WT3    = (uint16_t*)alloc((size_t)128 * 256 * 2);
  int* ptr_s       = (int*)alloc((size_t)(n + 1) * 4);
  int* ptr_t       = (int*)alloc((size_t)(n + 1) * 4);
  int* bcur        = (int*)alloc((size_t)2 * NB_MAX * 4);   // one memset covers both
  int* bcur_s      = bcur;
  int* bcur_t      = bcur + NB_MAX;
  uint64_t* kv2_s  = (uint64_t*)alloc((size_t)NB_MAX * KV_CAP * 8);
  uint64_t* kv2_t  = (uint64_t*)alloc((size_t)NB_MAX * KV_CAP * 8);
  uint32_t* c4_s   = (uint32_t*)alloc((size_t)ne * 4);
  uint32_t* c4_t   = (uint32_t*)alloc((size_t)ne * 4);

  Branch bs = { inp_s, idx_s, val_s, H_s, ptr_s, bcur_s, kv2_s, c4_s, out };
  Branch bt = { inp_t, idx_t, val_t, H_t, ptr_t, bcur_t, kv2_t, c4_t,
                out + (size_t)n * D_OUT };

  const int nblkE = (ne + 4095) / 4096;            // 391
  const int nblkG = (n + 127) / 128;               // 391
  const int nblkF = nblkE > nblkG ? nblkE : nblkG;
  const int bpb   = (((n + 15) / 16) + 3) & ~3;    // gather blocks per branch, %4==0

  hipMemsetAsync(bcur, 0, (size_t)2 * NB_MAX * 4, stream);
  wprep3_kernel<<<dim3(128), 256, 0, stream>>>(W, WT3);
  bin_gemm_kernel<<<dim3(nblkF, 2, 2), 256, 0, stream>>>(WT3, bs, bt, n, ne, nb);
  bucket_csr_kernel<<<dim3(nb, 2), 256, 0, stream>>>(bs, bt, n, nb);
  gather_kernel<<<dim3(2 * bpb), 256, 0, stream>>>(bs, bt, n);
}